// Round 4
// baseline (294.541 us; speedup 1.0000x reference)
//
#include <hip/hip_runtime.h>
#include <stdint.h>

// Shapes (fixed by problem)
#define DIMD 1024
#define HEADS 16
#define HD 64
#define SEQ 2048
#define NBATCH 2
#define TOKENS 4096
#define BH 32

typedef __bf16 bf16x8 __attribute__((ext_vector_type(8)));
typedef float f32x4 __attribute__((ext_vector_type(4)));

#if __has_builtin(__builtin_amdgcn_exp2f)
#define EXP2(x) __builtin_amdgcn_exp2f(x)
#else
#define EXP2(x) exp2f(x)
#endif

#if __has_builtin(__builtin_amdgcn_cvt_pk_bf16_f32)
typedef __bf16 bf16x2 __attribute__((ext_vector_type(2)));
__device__ inline unsigned int pack2(float a, float b) {
    bf16x2 r = __builtin_amdgcn_cvt_pk_bf16_f32(a, b);
    return __builtin_bit_cast(unsigned int, r);
}
__device__ inline unsigned short f2bf(float f) {
    bf16x2 r = __builtin_amdgcn_cvt_pk_bf16_f32(f, f);
    return (unsigned short)(__builtin_bit_cast(unsigned int, r) & 0xffffu);
}
#else
__device__ inline unsigned short f2bf(float f) {
    unsigned int u = __builtin_bit_cast(unsigned int, f) + 0x8000u;
    return (unsigned short)(u >> 16);
}
__device__ inline unsigned int pack2(float a, float b) {
    unsigned int ua = __builtin_bit_cast(unsigned int, a) + 0x8000u;
    unsigned int ub = __builtin_bit_cast(unsigned int, b) + 0x8000u;
    return (ua >> 16) | (ub & 0xffff0000u);
}
#endif

// async global->LDS, 16B per lane, dest = wave-uniform base + lane*16
__device__ inline void gl_lds16(const void* g, void* l) {
    __builtin_amdgcn_global_load_lds(
        (const __attribute__((address_space(1))) unsigned int*)g,
        (__attribute__((address_space(3))) unsigned int*)l, 16, 0, 0);
}

// log2(e) * DIM^-0.5  (folded into Q at GEMM1 epilogue)
#define CEQ 0.0450842200277801f

// ------------- prep: cast x -> bf16 AND transpose-cast both weights ----
__global__ __launch_bounds__(256) void prep(const float* __restrict__ x,
                                            const float* __restrict__ wqkv,
                                            const float* __restrict__ wout,
                                            short* __restrict__ xb,
                                            short* __restrict__ wqkvt,
                                            short* __restrict__ woutt) {
    __shared__ short T[64 * 68];
    int bid = blockIdx.x, t = threadIdx.x;
    if (bid < 2048) {
        int g = bid * 256 + t;
        const float4* p = (const float4*)x + (size_t)g * 2;
        float4 a = p[0], b = p[1];
        uint4 o;
        o.x = pack2(a.x, a.y); o.y = pack2(a.z, a.w);
        o.z = pack2(b.x, b.y); o.w = pack2(b.z, b.w);
        ((uint4*)xb)[g] = o;
        return;
    }
    const float* w; short* wt; int N, n0, k0;
    if (bid < 2816) { int l = bid - 2048; w = wqkv; wt = wqkvt; N = 3072; n0 = (l % 48) * 64; k0 = (l / 48) * 64; }
    else            { int l = bid - 2816; w = wout; wt = woutt; N = 1024; n0 = (l % 16) * 64; k0 = (l / 16) * 64; }
    for (int e = 0; e < 4; e++) {
        int lin = t + e * 256;
        int r = lin >> 4, c = (lin & 15) * 4;
        float4 v = *(const float4*)(w + (size_t)(k0 + r) * N + n0 + c);
        *(uint2*)&T[r * 68 + c] = make_uint2(pack2(v.x, v.y), pack2(v.z, v.w));
    }
    __syncthreads();
    for (int e = 0; e < 4; e++) {
        int lin = t + e * 256;
        int nr = lin >> 4, kc = (lin & 15) * 4;
        unsigned short a0 = (unsigned short)T[(kc + 0) * 68 + nr];
        unsigned short a1 = (unsigned short)T[(kc + 1) * 68 + nr];
        unsigned short a2 = (unsigned short)T[(kc + 2) * 68 + nr];
        unsigned short a3 = (unsigned short)T[(kc + 3) * 68 + nr];
        *(uint2*)(wt + (size_t)(n0 + nr) * 1024 + k0 + kc) =
            make_uint2((unsigned int)a0 | ((unsigned int)a1 << 16),
                       (unsigned int)a2 | ((unsigned int)a3 << 16));
    }
}

// ---------------- GEMM1 (r10-proven): 128x128 dbuf single-barrier ------
__global__ __launch_bounds__(256) void gemm_qkv(const short* __restrict__ A,
                                                const short* __restrict__ Bt,
                                                short* __restrict__ Qb,
                                                short* __restrict__ Kb,
                                                short* __restrict__ Vtb) {
    __shared__ short As[2][128 * 32];
    __shared__ short Bs[2][128 * 32];
    int gid = blockIdx.x;
    int sg = gid >> 4, wi = gid & 15;
    int mt = (sg / 6) * 4 + (wi >> 2);
    int nt = (sg % 6) * 4 + (wi & 3);
    int t = threadIdx.x, w = t >> 6, lane = t & 63, c = lane & 15, q = lane >> 4;
    int mw = (w & 1) * 64, nw = (w >> 1) * 64;
    int h3 = lane >> 3, s3 = lane & 7, cp = s3 ^ h3;
    int rowin = 2 * h3 + (cp >> 2), koff = (cp & 3) * 16;
    const char* Ag0 = (const char*)A + (size_t)(mt * 128 + w * 32 + rowin) * 2048 + koff;
    const char* Ag1 = Ag0 + (size_t)16 * 2048;
    const char* Bg0 = (const char*)Bt + (size_t)(nt * 128 + w * 32 + rowin) * 2048 + koff;
    const char* Bg1 = Bg0 + (size_t)16 * 2048;
    int cb = (c >> 1) * 128 + ((((c & 1) * 4 + q) ^ ((c >> 1) & 7)) * 16);
    f32x4 acc[4][4] = {};
    gl_lds16(Ag0, (char*)As[0] + w * 2048);
    gl_lds16(Ag1, (char*)As[0] + w * 2048 + 1024);
    gl_lds16(Bg0, (char*)Bs[0] + w * 2048);
    gl_lds16(Bg1, (char*)Bs[0] + w * 2048 + 1024);
    __syncthreads();
    for (int kt = 0; kt < 32; kt++) {
        int bu = kt & 1;
        if (kt < 31) {
            gl_lds16(Ag0 + (kt + 1) * 64, (char*)As[bu ^ 1] + w * 2048);
            gl_lds16(Ag1 + (kt + 1) * 64, (char*)As[bu ^ 1] + w * 2048 + 1024);
            gl_lds16(Bg0 + (kt + 1) * 64, (char*)Bs[bu ^ 1] + w * 2048);
            gl_lds16(Bg1 + (kt + 1) * 64, (char*)Bs[bu ^ 1] + w * 2048 + 1024);
        }
        bf16x8 af[4], bfr[4];
        for (int mf = 0; mf < 4; mf++)
            af[mf] = *(bf16x8*)((char*)As[bu] + (mw + mf * 16) * 64 + cb);
        for (int nf = 0; nf < 4; nf++)
            bfr[nf] = *(bf16x8*)((char*)Bs[bu] + (nw + nf * 16) * 64 + cb);
        for (int mf = 0; mf < 4; mf++)
            for (int nf = 0; nf < 4; nf++)
                acc[mf][nf] = __builtin_amdgcn_mfma_f32_16x16x32_bf16(
                    af[mf], bfr[nf], acc[mf][nf], 0, 0, 0);
        __syncthreads();
    }
    for (int nf = 0; nf < 4; nf++) {
        int col = nt * 128 + nw + nf * 16 + c;
        int sel = col >> 10, cw = col & 1023, h = cw >> 6, d = cw & 63;
        float sc = (sel == 0) ? CEQ : 1.0f;
        for (int mf = 0; mf < 4; mf++) {
            int m0 = mt * 128 + mw + mf * 16 + q * 4;
            int b = m0 >> 11, nn = m0 & 2047;
            int bh = b * 16 + h;
            if (sel == 2) {
                *(uint2*)(Vtb + ((size_t)bh * 64 + d) * 2048 + nn) =
                    make_uint2(pack2(acc[mf][nf][0], acc[mf][nf][1]),
                               pack2(acc[mf][nf][2], acc[mf][nf][3]));
            } else {
                short* dst = (sel ? Kb : Qb) + ((size_t)bh * 2048 + nn) * 64 + d;
                dst[0]   = (short)f2bf(acc[mf][nf][0] * sc);
                dst[64]  = (short)f2bf(acc[mf][nf][1] * sc);
                dst[128] = (short)f2bf(acc[mf][nf][2] * sc);
                dst[192] = (short)f2bf(acc[mf][nf][3] * sc);
            }
        }
    }
}

// ---------------- flash attention v11: V direct-to-registers (no V LDS),
// K triple-buffered with counted vmcnt + ONE raw barrier per jt.
// sigma K staging (v8-proven): LDS row [b5b4|b3|b2b1b0] <- source S-row
// [b5|b3 b2|b4|b1 b0], so QK^T C-layout == PV B-fragment (P in regs).
// V A-fragment = 16 contiguous bytes of Vtb[d][s] -> global_load_dwordx4
// straight into VGPRs, prefetched one jt ahead (T14). 10 vmem ops/jt in
// flight across the barrier; vmcnt(10) waits only the previous tile.
// fstep<JT> keeps all buffer/register indices compile-time constant.
template <int JT>
__device__ __forceinline__ void fstep(char* ktp, const char* Ksrc,
                                      const char* VgA, const char* VgB,
                                      const char* VgC, const char* VgD,
                                      bf16x8 (&VC)[8], bf16x8 (&VN)[8],
                                      const bf16x8 (&bq)[2][2],
                                      f32x4 (&of)[4][2], f32x4 (&lacc)[2],
                                      bf16x8 ones, int sw0, int sw1,
                                      int c, int hf, int wi) {
    if (JT < 15) {
        char* kb = ktp + ((JT + 1) % 3) * 16384 + hf * 8192 + wi * 2048;
        gl_lds16(Ksrc + (size_t)(JT + 1) * 8192, kb);
        gl_lds16(Ksrc + (size_t)(JT + 1) * 8192 + 2048, kb + 1024);
        VN[0] = *(const bf16x8*)(VgA + (JT + 1) * 128);
        VN[1] = *(const bf16x8*)(VgA + (JT + 1) * 128 + 64);
        VN[2] = *(const bf16x8*)(VgB + (JT + 1) * 128);
        VN[3] = *(const bf16x8*)(VgB + (JT + 1) * 128 + 64);
        VN[4] = *(const bf16x8*)(VgC + (JT + 1) * 128);
        VN[5] = *(const bf16x8*)(VgC + (JT + 1) * 128 + 64);
        VN[6] = *(const bf16x8*)(VgD + (JT + 1) * 128);
        VN[7] = *(const bf16x8*)(VgD + (JT + 1) * 128 + 64);
        asm volatile("s_waitcnt vmcnt(10)" ::: "memory");
    } else {
        asm volatile("s_waitcnt vmcnt(0)" ::: "memory");
    }
    __builtin_amdgcn_s_barrier();
    __builtin_amdgcn_sched_barrier(0);
    const char* kth = ktp + (JT % 3) * 16384 + hf * 8192;
    f32x4 st[4][2] = {};
    __builtin_amdgcn_s_setprio(1);
#pragma unroll
    for (int jf = 0; jf < 4; jf++) {
        bf16x8 ka0 = *(bf16x8*)(kth + (jf * 16 + c) * 128 + sw0);
        bf16x8 ka1 = *(bf16x8*)(kth + (jf * 16 + c) * 128 + sw1);
        st[jf][0] = __builtin_amdgcn_mfma_f32_16x16x32_bf16(ka0, bq[0][0], st[jf][0], 0, 0, 0);
        st[jf][1] = __builtin_amdgcn_mfma_f32_16x16x32_bf16(ka0, bq[1][0], st[jf][1], 0, 0, 0);
        st[jf][0] = __builtin_amdgcn_mfma_f32_16x16x32_bf16(ka1, bq[0][1], st[jf][0], 0, 0, 0);
        st[jf][1] = __builtin_amdgcn_mfma_f32_16x16x32_bf16(ka1, bq[1][1], st[jf][1], 0, 0, 0);
    }
    __builtin_amdgcn_s_setprio(0);
#pragma unroll
    for (int ks = 0; ks < 2; ks++) {
        bf16x8 pb[2];
#pragma unroll
        for (int i2 = 0; i2 < 2; i2++) {
            f32x4 sa = st[2 * ks][i2], sb = st[2 * ks + 1][i2];
            uint4 uu;
            uu.x = pack2(EXP2(sa[0]), EXP2(sa[1]));
            uu.y = pack2(EXP2(sa[2]), EXP2(sa[3]));
            uu.z = pack2(EXP2(sb[0]), EXP2(sb[1]));
            uu.w = pack2(EXP2(sb[2]), EXP2(sb[3]));
            pb[i2] = __builtin_bit_cast(bf16x8, uu);
        }
        __builtin_amdgcn_s_setprio(1);
#pragma unroll
        for (int mf = 0; mf < 4; mf++) {
            bf16x8 va = VC[mf * 2 + ks];
            of[mf][0] = __builtin_amdgcn_mfma_f32_16x16x32_bf16(va, pb[0], of[mf][0], 0, 0, 0);
            of[mf][1] = __builtin_amdgcn_mfma_f32_16x16x32_bf16(va, pb[1], of[mf][1], 0, 0, 0);
        }
        lacc[0] = __builtin_amdgcn_mfma_f32_16x16x32_bf16(ones, pb[0], lacc[0], 0, 0, 0);
        lacc[1] = __builtin_amdgcn_mfma_f32_16x16x32_bf16(ones, pb[1], lacc[1], 0, 0, 0);
        __builtin_amdgcn_s_setprio(0);
    }
}

__global__ __launch_bounds__(512, 4) void flash_attn(const short* __restrict__ Qb,
                                                     const short* __restrict__ Kb,
                                                     const short* __restrict__ Vtb,
                                                     short* __restrict__ Ob) {
    __shared__ __align__(16) char smem[51712];
    char* ktp = smem;                         // 3 x 16384 K triple-buffer
    float* lxp = (float*)(smem + 51200);
    int bh = blockIdx.x, qt = blockIdx.y;
    int t = threadIdx.x, w = t >> 6, lane = t & 63, c = lane & 15, q = lane >> 4;
    int wi = w & 3, hf = w >> 2;
    const short* Qh = Qb + (size_t)bh * SEQ * HD;
    bf16x8 bq[2][2];
    for (int i2 = 0; i2 < 2; i2++)
        for (int ks = 0; ks < 2; ks++)
            bq[i2][ks] = *(const bf16x8*)(Qh + (size_t)(qt * 128 + wi * 32 + i2 * 16 + c) * 64 + ks * 32 + q * 8);
    int rl = lane >> 3, sl = lane & 7, ch = sl ^ rl;
    // sigma-permuted K source row (within the 64-row jt tile), e adds +16:
    //   srow(e) = (wi>>1)*32 + e*16 + (rl>>2)*8 + (wi&1)*4 + (rl&3)
    int srow0 = (wi >> 1) * 32 + (rl >> 2) * 8 + (wi & 1) * 4 + (rl & 3);
    const char* Ksrc = (const char*)(Kb + (size_t)bh * SEQ * HD)
                       + (size_t)(hf * 1024 + srow0) * 128 + ch * 16;
    // V direct-load lane base pointers: row d = mf*16+c, byte = d*4096 +
    // hf*2048 + jt*128 + ks*64 + q*16  (s = hf*1024 + jt*64 + ks*32 + q*8)
    const char* Vh = (const char*)(Vtb + (size_t)bh * HD * SEQ) + hf * 2048 + q * 16;
    const char* VgA = Vh + (size_t)(0 * 16 + c) * 4096;
    const char* VgB = Vh + (size_t)(1 * 16 + c) * 4096;
    const char* VgC = Vh + (size_t)(2 * 16 + c) * 4096;
    const char* VgD = Vh + (size_t)(3 * 16 + c) * 4096;
    int sw0 = (q ^ (c & 7)) * 16;
    int sw1 = ((4 + q) ^ (c & 7)) * 16;
    bf16x8 ones;
    {
        unsigned short ob = 0x3F80;
        __bf16 ov = __builtin_bit_cast(__bf16, ob);
        for (int e = 0; e < 8; e++) ones[e] = ov;
    }
    f32x4 lacc[2] = {};
    f32x4 of[4][2] = {};
    bf16x8 vfA[8], vfB[8];
    // prologue: K(0) -> buf0, V(0) -> vfA
    {
        char* kb = ktp + hf * 8192 + wi * 2048;
        gl_lds16(Ksrc, kb);
        gl_lds16(Ksrc + 2048, kb + 1024);
        vfA[0] = *(const bf16x8*)(VgA);
        vfA[1] = *(const bf16x8*)(VgA + 64);
        vfA[2] = *(const bf16x8*)(VgB);
        vfA[3] = *(const bf16x8*)(VgB + 64);
        vfA[4] = *(const bf16x8*)(VgC);
        vfA[5] = *(const bf16x8*)(VgC + 64);
        vfA[6] = *(const bf16x8*)(VgD);
        vfA[7] = *(const bf16x8*)(VgD + 64);
    }
    fstep<0>(ktp, Ksrc, VgA, VgB, VgC, VgD, vfA, vfB, bq, of, lacc, ones, sw0, sw1, c, hf, wi);
    fstep<1>(ktp, Ksrc, VgA, VgB, VgC, VgD, vfB, vfA, bq, of, lacc, ones, sw0, sw1, c, hf, wi);
    fstep<2>(ktp, Ksrc, VgA, VgB, VgC, VgD, vfA, vfB, bq, of, lacc, ones, sw0, sw1, c, hf, wi);
    fstep<3>(ktp, Ksrc, VgA, VgB, VgC, VgD, vfB, vfA, bq, of, lacc, ones, sw0, sw1, c, hf, wi);
    fstep<4>(ktp, Ksrc, VgA, VgB, VgC, VgD, vfA, vfB, bq, of, lacc, ones, sw0, sw1, c, hf, wi);
    fstep<5>(ktp, Ksrc, VgA, VgB, VgC, VgD, vfB, vfA, bq, of, lacc, ones, sw0, sw1, c, hf, wi);
    fstep<6>(ktp, Ksrc, VgA, VgB, VgC, VgD, vfA, vfB, bq, of, lacc, ones, sw0, sw1, c, hf, wi);
    fstep<7>(ktp, Ksrc, VgA, VgB, VgC, VgD, vfB, vfA, bq, of, lacc, ones, sw0, sw1, c, hf, wi);
    fstep<8>(ktp, Ksrc, VgA, VgB, VgC, VgD, vfA, vfB, bq, of, lacc, ones, sw0, sw1, c, hf, wi);
    fstep<9>(ktp, Ksrc, VgA, VgB, VgC, VgD, vfB, vfA, bq, of, lacc, ones, sw0, sw1, c, hf, wi);
    fstep<10>(ktp, Ksrc, VgA, VgB, VgC, VgD, vfA, vfB, bq, of, lacc, ones, sw0, sw1, c, hf, wi);
    fstep<11>(ktp, Ksrc, VgA, VgB, VgC, VgD, vfB, vfA, bq, of, lacc, ones, sw0, sw1, c, hf, wi);
    fstep<12>(ktp, Ksrc, VgA, VgB, VgC, VgD, vfA, vfB, bq, of, lacc, ones, sw0, sw1, c, hf, wi);
    fstep<13>(ktp, Ksrc, VgA, VgB, VgC, VgD, vfB, vfA, bq, of, lacc, ones, sw0, sw1, c, hf, wi);
    fstep<14>(ktp, Ksrc, VgA, VgB, VgC, VgD, vfA, vfB, bq, of, lacc, ones, sw0, sw1, c, hf, wi);
    fstep<15>(ktp, Ksrc, VgA, VgB, VgC, VgD, vfB, vfA, bq, of, lacc, ones, sw0, sw1, c, hf, wi);
    __syncthreads();   // all K reads consumed; smem reused below
    float l0 = lacc[0][0], l1 = lacc[1][0];
    if (w >= 4) {
        float* ex = (float*)smem + (w - 4) * 2048;
        for (int mf = 0; mf < 4; mf++)
            for (int i2 = 0; i2 < 2; i2++)
                *(f32x4*)(ex + (mf * 2 + i2) * 256 + lane * 4) = of[mf][i2];
        if (lane < 16) { lxp[(w - 4) * 32 + lane] = l0; lxp[(w - 4) * 32 + 16 + lane] = l1; }
    }
    __syncthreads();
    if (w < 4) {
        float* ex = (float*)smem + w * 2048;
        for (int mf = 0; mf < 4; mf++)
            for (int i2 = 0; i2 < 2; i2++)
                of[mf][i2] += *(f32x4*)(ex + (mf * 2 + i2) * 256 + lane * 4);
        l0 += lxp[w * 32 + c];
        l1 += lxp[w * 32 + 16 + c];
        float inv0 = 1.f / l0, inv1 = 1.f / l1;
        short* plw = (short*)(smem + 32768 + w * 4608);
        for (int mf = 0; mf < 4; mf++) {
            *(uint2*)(plw + (0 * 16 + c) * 72 + mf * 16 + q * 4) =
                make_uint2(pack2(of[mf][0][0] * inv0, of[mf][0][1] * inv0),
                           pack2(of[mf][0][2] * inv0, of[mf][0][3] * inv0));
            *(uint2*)(plw + (1 * 16 + c) * 72 + mf * 16 + q * 4) =
                make_uint2(pack2(of[mf][1][0] * inv1, of[mf][1][1] * inv1),
                           pack2(of[mf][1][2] * inv1, of[mf][1][3] * inv1));
        }
        int b2 = bh >> 4, h = bh & 15;
        for (int e = 0; e < 4; e++) {
            int chn = e * 64 + lane;
            int i = chn >> 3, db = (chn & 7) * 16;
            float4 v = *(float4*)((char*)plw + i * 144 + db);
            int token = b2 * 2048 + qt * 128 + w * 32 + i;
            *(float4*)((char*)Ob + (size_t)token * 2048 + h * 128 + db) = v;
        }
    }
}

// ---------------- GEMM2 (r12-proven): plain stores, 512 blocks ---------
__global__ __launch_bounds__(256) void gemm_out(const short* __restrict__ A,
                                                const short* __restrict__ Bt,
                                                const float* __restrict__ bias,
                                                float* __restrict__ out) {
    __shared__ short As[2][128 * 32];
    __shared__ short Bs[2][64 * 32];
    int gid = blockIdx.x;
    int sg = gid >> 4, wi = gid & 15;
    int mt = (sg / 4) * 4 + (wi >> 2);
    int nt = (sg % 4) * 4 + (wi & 3);
    int t = threadIdx.x, w = t >> 6, lane = t & 63, c = lane & 15, q = lane >> 4;
    int mw = (w & 1) * 64, nw = (w >> 1) * 32;
    int h3 = lane >> 3, s3 = lane & 7, cp = s3 ^ h3;
    int rowin = 2 * h3 + (cp >> 2), koff = (cp & 3) * 16;
    const char* Ag0 = (const char*)A + (size_t)(mt * 128 + w * 32 + rowin) * 2048 + koff;
    const char* Ag1 = Ag0 + (size_t)16 * 2048;
    const char* Bg0 = (const char*)Bt + (size_t)(nt * 64 + w * 16 + rowin) * 2048 + koff;
    int cb = (c >> 1) * 128 + ((((c & 1) * 4 + q) ^ ((c >> 1) & 7)) * 16);
    f32x4 acc[4][2] = {};
    gl_lds16(Ag0, (char*)As[0] + w * 2048);
    gl_lds16(Ag1, (char*)As[0] + w * 2048 + 1024);
    gl_lds16(Bg0, (char*)Bs[0] + w * 1024);
    __syncthreads();
    for (int kt = 0; kt < 32; kt++) {
        int bu = kt & 1;
        if (kt < 31) {
            gl_lds16(Ag0 + (kt + 1) * 64, (char*)As[bu ^ 1] + w * 2048);
            gl_lds16(Ag1 + (kt + 1) * 64, (char*)As[bu ^ 1] + w * 2048 + 1024);
            gl_lds16(Bg0 + (kt + 1) * 64, (char*)Bs[bu ^ 1] + w * 1024);
        }
        bf16x8 af[4], bfr[2];
        for (int mf = 0; mf < 4; mf++)
            af[mf] = *(bf16x8*)((char*)As[bu] + (mw + mf * 16) * 64 + cb);
        for (int nf = 0; nf < 2; nf++)
            bfr[nf] = *(bf16x8*)((char*)Bs[bu] + (nw + nf * 16) * 64 + cb);
        for (int mf = 0; mf < 4; mf++)
            for (int nf = 0; nf < 2; nf++)
                acc[mf][nf] = __builtin_amdgcn_mfma_f32_16x16x32_bf16(
                    af[mf], bfr[nf], acc[mf][nf], 0, 0, 0);
        __syncthreads();
    }
    for (int nf = 0; nf < 2; nf++) {
        int col = nt * 64 + nw + nf * 16 + c;
        float bv = bias[col];
        for (int mf = 0; mf < 4; mf++) {
            int m0 = mt * 128 + mw + mf * 16 + q * 4;
            float* dst = out + (size_t)m0 * 1024 + col;
            dst[0]    = acc[mf][nf][0] + bv;
            dst[1024] = acc[mf][nf][1] + bv;
            dst[2048] = acc[mf][nf][2] + bv;
            dst[3072] = acc[mf][nf][3] + bv;
        }
    }
}

extern "C" void kernel_launch(void* const* d_in, const int* in_sizes, int n_in,
                              void* d_out, int out_size, void* d_ws, size_t ws_size,
                              hipStream_t stream) {
    (void)in_sizes; (void)n_in; (void)out_size; (void)ws_size;
    const float* x     = (const float*)d_in[0];
    const float* w_qkv = (const float*)d_in[1];
    const float* w_out = (const float*)d_in[2];
    const float* b_out = (const float*)d_in[3];
    float* out = (float*)d_out;

    short* xb    = (short*)d_ws;
    short* wqkvt = xb    + 4096 * 1024;
    short* woutt = wqkvt + 3072 * 1024;
    short* Qb    = woutt + 1024 * 1024;
    short* Kb    = Qb    + BH * SEQ * HD;
    short* Vtb   = Kb    + BH * SEQ * HD;
    short* Ob    = Vtb   + BH * HD * SEQ;

    hipLaunchKernelGGL(prep, dim3(3072), dim3(256), 0, stream, x, w_qkv, w_out, xb, wqkvt, woutt);
    hipLaunchKernelGGL(gemm_qkv, dim3(768), dim3(256), 0, stream, xb, wqkvt, Qb, Kb, Vtb);
    hipLaunchKernelGGL(flash_attn, dim3(32, 16), dim3(512), 0, stream, Qb, Kb, Vtb, Ob);
    hipLaunchKernelGGL(gemm_out, dim3(512), dim3(256), 0, stream, Ob, woutt, b_out, out);
}

// Round 5
// 206.034 us; speedup vs baseline: 1.4296x; 1.4296x over previous
//
#include <hip/hip_runtime.h>
#include <stdint.h>

// Shapes (fixed by problem)
#define DIMD 1024
#define HEADS 16
#define HD 64
#define SEQ 2048
#define NBATCH 2
#define TOKENS 4096
#define BH 32

typedef __bf16 bf16x8 __attribute__((ext_vector_type(8)));
typedef float f32x4 __attribute__((ext_vector_type(4)));

#if __has_builtin(__builtin_amdgcn_exp2f)
#define EXP2(x) __builtin_amdgcn_exp2f(x)
#else
#define EXP2(x) exp2f(x)
#endif

#if __has_builtin(__builtin_amdgcn_cvt_pk_bf16_f32)
typedef __bf16 bf16x2 __attribute__((ext_vector_type(2)));
__device__ inline unsigned int pack2(float a, float b) {
    bf16x2 r = __builtin_amdgcn_cvt_pk_bf16_f32(a, b);
    return __builtin_bit_cast(unsigned int, r);
}
__device__ inline unsigned short f2bf(float f) {
    bf16x2 r = __builtin_amdgcn_cvt_pk_bf16_f32(f, f);
    return (unsigned short)(__builtin_bit_cast(unsigned int, r) & 0xffffu);
}
#else
__device__ inline unsigned short f2bf(float f) {
    unsigned int u = __builtin_bit_cast(unsigned int, f) + 0x8000u;
    return (unsigned short)(u >> 16);
}
__device__ inline unsigned int pack2(float a, float b) {
    unsigned int ua = __builtin_bit_cast(unsigned int, a) + 0x8000u;
    unsigned int ub = __builtin_bit_cast(unsigned int, b) + 0x8000u;
    return (ua >> 16) | (ub & 0xffff0000u);
}
#endif

// async global->LDS, 16B per lane, dest = wave-uniform base + lane*16
__device__ inline void gl_lds16(const void* g, void* l) {
    __builtin_amdgcn_global_load_lds(
        (const __attribute__((address_space(1))) unsigned int*)g,
        (__attribute__((address_space(3))) unsigned int*)l, 16, 0, 0);
}

// log2(e) * DIM^-0.5  (folded into Q at GEMM1 epilogue)
#define CEQ 0.0450842200277801f

// ------------- prep: cast x -> bf16 AND transpose-cast both weights ----
__global__ __launch_bounds__(256) void prep(const float* __restrict__ x,
                                            const float* __restrict__ wqkv,
                                            const float* __restrict__ wout,
                                            short* __restrict__ xb,
                                            short* __restrict__ wqkvt,
                                            short* __restrict__ woutt) {
    __shared__ short T[64 * 68];
    int bid = blockIdx.x, t = threadIdx.x;
    if (bid < 2048) {
        int g = bid * 256 + t;
        const float4* p = (const float4*)x + (size_t)g * 2;
        float4 a = p[0], b = p[1];
        uint4 o;
        o.x = pack2(a.x, a.y); o.y = pack2(a.z, a.w);
        o.z = pack2(b.x, b.y); o.w = pack2(b.z, b.w);
        ((uint4*)xb)[g] = o;
        return;
    }
    const float* w; short* wt; int N, n0, k0;
    if (bid < 2816) { int l = bid - 2048; w = wqkv; wt = wqkvt; N = 3072; n0 = (l % 48) * 64; k0 = (l / 48) * 64; }
    else            { int l = bid - 2816; w = wout; wt = woutt; N = 1024; n0 = (l % 16) * 64; k0 = (l / 16) * 64; }
    for (int e = 0; e < 4; e++) {
        int lin = t + e * 256;
        int r = lin >> 4, c = (lin & 15) * 4;
        float4 v = *(const float4*)(w + (size_t)(k0 + r) * N + n0 + c);
        *(uint2*)&T[r * 68 + c] = make_uint2(pack2(v.x, v.y), pack2(v.z, v.w));
    }
    __syncthreads();
    for (int e = 0; e < 4; e++) {
        int lin = t + e * 256;
        int nr = lin >> 4, kc = (lin & 15) * 4;
        unsigned short a0 = (unsigned short)T[(kc + 0) * 68 + nr];
        unsigned short a1 = (unsigned short)T[(kc + 1) * 68 + nr];
        unsigned short a2 = (unsigned short)T[(kc + 2) * 68 + nr];
        unsigned short a3 = (unsigned short)T[(kc + 3) * 68 + nr];
        *(uint2*)(wt + (size_t)(n0 + nr) * 1024 + k0 + kc) =
            make_uint2((unsigned int)a0 | ((unsigned int)a1 << 16),
                       (unsigned int)a2 | ((unsigned int)a3 << 16));
    }
}

// ---------------- GEMM1 (r10-proven): 128x128 dbuf single-barrier ------
__global__ __launch_bounds__(256) void gemm_qkv(const short* __restrict__ A,
                                                const short* __restrict__ Bt,
                                                short* __restrict__ Qb,
                                                short* __restrict__ Kb,
                                                short* __restrict__ Vtb) {
    __shared__ short As[2][128 * 32];
    __shared__ short Bs[2][128 * 32];
    int gid = blockIdx.x;
    int sg = gid >> 4, wi = gid & 15;
    int mt = (sg / 6) * 4 + (wi >> 2);
    int nt = (sg % 6) * 4 + (wi & 3);
    int t = threadIdx.x, w = t >> 6, lane = t & 63, c = lane & 15, q = lane >> 4;
    int mw = (w & 1) * 64, nw = (w >> 1) * 64;
    int h3 = lane >> 3, s3 = lane & 7, cp = s3 ^ h3;
    int rowin = 2 * h3 + (cp >> 2), koff = (cp & 3) * 16;
    const char* Ag0 = (const char*)A + (size_t)(mt * 128 + w * 32 + rowin) * 2048 + koff;
    const char* Ag1 = Ag0 + (size_t)16 * 2048;
    const char* Bg0 = (const char*)Bt + (size_t)(nt * 128 + w * 32 + rowin) * 2048 + koff;
    const char* Bg1 = Bg0 + (size_t)16 * 2048;
    int cb = (c >> 1) * 128 + ((((c & 1) * 4 + q) ^ ((c >> 1) & 7)) * 16);
    f32x4 acc[4][4] = {};
    gl_lds16(Ag0, (char*)As[0] + w * 2048);
    gl_lds16(Ag1, (char*)As[0] + w * 2048 + 1024);
    gl_lds16(Bg0, (char*)Bs[0] + w * 2048);
    gl_lds16(Bg1, (char*)Bs[0] + w * 2048 + 1024);
    __syncthreads();
    for (int kt = 0; kt < 32; kt++) {
        int bu = kt & 1;
        if (kt < 31) {
            gl_lds16(Ag0 + (kt + 1) * 64, (char*)As[bu ^ 1] + w * 2048);
            gl_lds16(Ag1 + (kt + 1) * 64, (char*)As[bu ^ 1] + w * 2048 + 1024);
            gl_lds16(Bg0 + (kt + 1) * 64, (char*)Bs[bu ^ 1] + w * 2048);
            gl_lds16(Bg1 + (kt + 1) * 64, (char*)Bs[bu ^ 1] + w * 2048 + 1024);
        }
        bf16x8 af[4], bfr[4];
        for (int mf = 0; mf < 4; mf++)
            af[mf] = *(bf16x8*)((char*)As[bu] + (mw + mf * 16) * 64 + cb);
        for (int nf = 0; nf < 4; nf++)
            bfr[nf] = *(bf16x8*)((char*)Bs[bu] + (nw + nf * 16) * 64 + cb);
        for (int mf = 0; mf < 4; mf++)
            for (int nf = 0; nf < 4; nf++)
                acc[mf][nf] = __builtin_amdgcn_mfma_f32_16x16x32_bf16(
                    af[mf], bfr[nf], acc[mf][nf], 0, 0, 0);
        __syncthreads();
    }
    for (int nf = 0; nf < 4; nf++) {
        int col = nt * 128 + nw + nf * 16 + c;
        int sel = col >> 10, cw = col & 1023, h = cw >> 6, d = cw & 63;
        float sc = (sel == 0) ? CEQ : 1.0f;
        for (int mf = 0; mf < 4; mf++) {
            int m0 = mt * 128 + mw + mf * 16 + q * 4;
            int b = m0 >> 11, nn = m0 & 2047;
            int bh = b * 16 + h;
            if (sel == 2) {
                *(uint2*)(Vtb + ((size_t)bh * 64 + d) * 2048 + nn) =
                    make_uint2(pack2(acc[mf][nf][0], acc[mf][nf][1]),
                               pack2(acc[mf][nf][2], acc[mf][nf][3]));
            } else {
                short* dst = (sel ? Kb : Qb) + ((size_t)bh * 2048 + nn) * 64 + d;
                dst[0]   = (short)f2bf(acc[mf][nf][0] * sc);
                dst[64]  = (short)f2bf(acc[mf][nf][1] * sc);
                dst[128] = (short)f2bf(acc[mf][nf][2] * sc);
                dst[192] = (short)f2bf(acc[mf][nf][3] * sc);
            }
        }
    }
}

// ---------------- flash attention v12: v11 schedule, register-economized.
// K triple-buffered (counted vmcnt, 1 raw barrier/jt); V direct-to-reg
// with a SINGLE 8-reg buffer (loads for jt+1 issued after last PV read
// of jt; WAR safe in-order; latency hides under K-issue+barrier+QK of
// jt+1 + compiler auto-wait). Split-ks QK keeps st at 16 regs. l-sums
// accumulated as 2 scalar f32/lane (shfl_xor(16/32) reduce at end)
// instead of ones-MFMA -> total ~122 unified regs, fits the 128 cap of
// __launch_bounds__(512,4) with no scratch.
__global__ __launch_bounds__(512, 4) void flash_attn(const short* __restrict__ Qb,
                                                     const short* __restrict__ Kb,
                                                     const short* __restrict__ Vtb,
                                                     short* __restrict__ Ob) {
    __shared__ __align__(16) char smem[51712];
    char* ktp = smem;                         // 3 x 16384 K triple-buffer
    float* lxp = (float*)(smem + 51200);
    int bh = blockIdx.x, qt = blockIdx.y;
    int t = threadIdx.x, w = t >> 6, lane = t & 63, c = lane & 15, q = lane >> 4;
    int wi = w & 3, hf = w >> 2;
    const short* Qh = Qb + (size_t)bh * SEQ * HD;
    bf16x8 bq[2][2];
    for (int i2 = 0; i2 < 2; i2++)
        for (int ks = 0; ks < 2; ks++)
            bq[i2][ks] = *(const bf16x8*)(Qh + (size_t)(qt * 128 + wi * 32 + i2 * 16 + c) * 64 + ks * 32 + q * 8);
    int rl = lane >> 3, sl = lane & 7, ch = sl ^ rl;
    // sigma-permuted K source row (within the 64-row jt tile):
    //   srow(e) = (wi>>1)*32 + e*16 + (rl>>2)*8 + (wi&1)*4 + (rl&3)
    int srow0 = (wi >> 1) * 32 + (rl >> 2) * 8 + (wi & 1) * 4 + (rl & 3);
    const char* Ksrc = (const char*)(Kb + (size_t)bh * SEQ * HD)
                       + (size_t)(hf * 1024 + srow0) * 128 + ch * 16;
    // V direct-load lane pointers: row d = X*16+c, byte = d*4096 +
    // hf*2048 + jt*128 + ks*64 + q*16  (s = hf*1024 + jt*64 + ks*32 + q*8)
    const char* VgA = (const char*)(Vtb + (size_t)bh * HD * SEQ)
                      + hf * 2048 + q * 16 + (size_t)c * 4096;
    const char* VgB = VgA + 65536;
    const char* VgC = VgA + 131072;
    const char* VgD = VgA + 196608;
    int sw0 = (q ^ (c & 7)) * 16;
    int sw1 = ((4 + q) ^ (c & 7)) * 16;
    f32x4 of[4][2] = {};
    float lsum[2] = {0.f, 0.f};
    bf16x8 vf[8];
    int kdo = hf * 8192 + wi * 2048;
    char* b0 = ktp;
    char* b1 = ktp + 16384;
    char* b2 = ktp + 32768;
    // prologue: K(0) -> b0, V(0) -> vf
    gl_lds16(Ksrc, b0 + kdo);
    gl_lds16(Ksrc + 2048, b0 + kdo + 1024);
    vf[0] = *(const bf16x8*)(VgA);      vf[1] = *(const bf16x8*)(VgA + 64);
    vf[2] = *(const bf16x8*)(VgB);      vf[3] = *(const bf16x8*)(VgB + 64);
    vf[4] = *(const bf16x8*)(VgC);      vf[5] = *(const bf16x8*)(VgC + 64);
    vf[6] = *(const bf16x8*)(VgD);      vf[7] = *(const bf16x8*)(VgD + 64);
#pragma unroll
    for (int jt = 0; jt < 16; jt++) {
        if (jt < 15) {
            // stage K(jt+1) into next buffer (dest last read in jt-2: safe)
            gl_lds16(Ksrc + (size_t)(jt + 1) * 8192, b1 + kdo);
            gl_lds16(Ksrc + (size_t)(jt + 1) * 8192 + 2048, b1 + kdo + 1024);
            // outstanding: K(jt)2 + V(jt)8 + K(jt+1)2 = 12 -> drain K(jt) only
            asm volatile("s_waitcnt vmcnt(10)" ::: "memory");
        } else {
            // outstanding: K(15)2 + V(15)8 = 10 -> drain K(15) only
            asm volatile("s_waitcnt vmcnt(8)" ::: "memory");
        }
        __builtin_amdgcn_s_barrier();
        __builtin_amdgcn_sched_barrier(0);
        const char* kth = b0 + hf * 8192;
#pragma unroll
        for (int ks = 0; ks < 2; ks++) {
            f32x4 st[2][2] = {};
            __builtin_amdgcn_s_setprio(1);
#pragma unroll
            for (int jf2 = 0; jf2 < 2; jf2++) {
                int jf = ks * 2 + jf2;
                bf16x8 ka0 = *(bf16x8*)(kth + (jf * 16 + c) * 128 + sw0);
                bf16x8 ka1 = *(bf16x8*)(kth + (jf * 16 + c) * 128 + sw1);
                st[jf2][0] = __builtin_amdgcn_mfma_f32_16x16x32_bf16(ka0, bq[0][0], st[jf2][0], 0, 0, 0);
                st[jf2][1] = __builtin_amdgcn_mfma_f32_16x16x32_bf16(ka0, bq[1][0], st[jf2][1], 0, 0, 0);
                st[jf2][0] = __builtin_amdgcn_mfma_f32_16x16x32_bf16(ka1, bq[0][1], st[jf2][0], 0, 0, 0);
                st[jf2][1] = __builtin_amdgcn_mfma_f32_16x16x32_bf16(ka1, bq[1][1], st[jf2][1], 0, 0, 0);
            }
            __builtin_amdgcn_s_setprio(0);
            // exp2 + f32 l-sum + pack into PV B-fragment (P stays in regs)
            bf16x8 pb[2];
#pragma unroll
            for (int i2 = 0; i2 < 2; i2++) {
                f32x4 sa = st[0][i2], sb = st[1][i2];
                float e0 = EXP2(sa[0]), e1 = EXP2(sa[1]), e2 = EXP2(sa[2]), e3 = EXP2(sa[3]);
                float e4 = EXP2(sb[0]), e5 = EXP2(sb[1]), e6 = EXP2(sb[2]), e7 = EXP2(sb[3]);
                lsum[i2] += ((e0 + e1) + (e2 + e3)) + ((e4 + e5) + (e6 + e7));
                uint4 uu;
                uu.x = pack2(e0, e1); uu.y = pack2(e2, e3);
                uu.z = pack2(e4, e5); uu.w = pack2(e6, e7);
                pb[i2] = __builtin_bit_cast(bf16x8, uu);
            }
            __builtin_amdgcn_s_setprio(1);
#pragma unroll
            for (int mf = 0; mf < 4; mf++) {
                bf16x8 va = vf[mf * 2 + ks];
                of[mf][0] = __builtin_amdgcn_mfma_f32_16x16x32_bf16(va, pb[0], of[mf][0], 0, 0, 0);
                of[mf][1] = __builtin_amdgcn_mfma_f32_16x16x32_bf16(va, pb[1], of[mf][1], 0, 0, 0);
            }
            __builtin_amdgcn_s_setprio(0);
        }
        if (jt < 15) {
            // V(jt+1) into the same regs: issued after last PV read (WAR safe)
            vf[0] = *(const bf16x8*)(VgA + (jt + 1) * 128);
            vf[1] = *(const bf16x8*)(VgA + (jt + 1) * 128 + 64);
            vf[2] = *(const bf16x8*)(VgB + (jt + 1) * 128);
            vf[3] = *(const bf16x8*)(VgB + (jt + 1) * 128 + 64);
            vf[4] = *(const bf16x8*)(VgC + (jt + 1) * 128);
            vf[5] = *(const bf16x8*)(VgC + (jt + 1) * 128 + 64);
            vf[6] = *(const bf16x8*)(VgD + (jt + 1) * 128);
            vf[7] = *(const bf16x8*)(VgD + (jt + 1) * 128 + 64);
        }
        char* tb = b0; b0 = b1; b1 = b2; b2 = tb;
    }
    // cross-lane reduce l over q (lanes differing in bits 4-5, same c)
    float l0 = lsum[0], l1 = lsum[1];
    l0 += __shfl_xor(l0, 16, 64);
    l0 += __shfl_xor(l0, 32, 64);
    l1 += __shfl_xor(l1, 16, 64);
    l1 += __shfl_xor(l1, 32, 64);
    __syncthreads();   // all K reads consumed; smem reused below
    if (w >= 4) {
        float* ex = (float*)smem + (w - 4) * 2048;
        for (int mf = 0; mf < 4; mf++)
            for (int i2 = 0; i2 < 2; i2++)
                *(f32x4*)(ex + (mf * 2 + i2) * 256 + lane * 4) = of[mf][i2];
        if (lane < 16) { lxp[(w - 4) * 32 + lane] = l0; lxp[(w - 4) * 32 + 16 + lane] = l1; }
    }
    __syncthreads();
    if (w < 4) {
        float* ex = (float*)smem + w * 2048;
        for (int mf = 0; mf < 4; mf++)
            for (int i2 = 0; i2 < 2; i2++)
                of[mf][i2] += *(f32x4*)(ex + (mf * 2 + i2) * 256 + lane * 4);
        l0 += lxp[w * 32 + c];
        l1 += lxp[w * 32 + 16 + c];
        float inv0 = 1.f / l0, inv1 = 1.f / l1;
        short* plw = (short*)(smem + 32768 + w * 4608);
        for (int mf = 0; mf < 4; mf++) {
            *(uint2*)(plw + (0 * 16 + c) * 72 + mf * 16 + q * 4) =
                make_uint2(pack2(of[mf][0][0] * inv0, of[mf][0][1] * inv0),
                           pack2(of[mf][0][2] * inv0, of[mf][0][3] * inv0));
            *(uint2*)(plw + (1 * 16 + c) * 72 + mf * 16 + q * 4) =
                make_uint2(pack2(of[mf][1][0] * inv1, of[mf][1][1] * inv1),
                           pack2(of[mf][1][2] * inv1, of[mf][1][3] * inv1));
        }
        int b2i = bh >> 4, h = bh & 15;
        for (int e = 0; e < 4; e++) {
            int chn = e * 64 + lane;
            int i = chn >> 3, db = (chn & 7) * 16;
            float4 v = *(float4*)((char*)plw + i * 144 + db);
            int token = b2i * 2048 + qt * 128 + w * 32 + i;
            *(float4*)((char*)Ob + (size_t)token * 2048 + h * 128 + db) = v;
        }
    }
}

// ---------------- GEMM2 (r12-proven): plain stores, 512 blocks ---------
__global__ __launch_bounds__(256) void gemm_out(const short* __restrict__ A,
                                                const short* __restrict__ Bt,
                                                const float* __restrict__ bias,
                                                float* __restrict__ out) {
    __shared__ short As[2][128 * 32];
    __shared__ short Bs[2][64 * 32];
    int gid = blockIdx.x;
    int sg = gid >> 4, wi = gid & 15;
    int mt = (sg / 4) * 4 + (wi >> 2);
    int nt = (sg % 4) * 4 + (wi & 3);
    int t = threadIdx.x, w = t >> 6, lane = t & 63, c = lane & 15, q = lane >> 4;
    int mw = (w & 1) * 64, nw = (w >> 1) * 32;
    int h3 = lane >> 3, s3 = lane & 7, cp = s3 ^ h3;
    int rowin = 2 * h3 + (cp >> 2), koff = (cp & 3) * 16;
    const char* Ag0 = (const char*)A + (size_t)(mt * 128 + w * 32 + rowin) * 2048 + koff;
    const char* Ag1 = Ag0 + (size_t)16 * 2048;
    const char* Bg0 = (const char*)Bt + (size_t)(nt * 64 + w * 16 + rowin) * 2048 + koff;
    int cb = (c >> 1) * 128 + ((((c & 1) * 4 + q) ^ ((c >> 1) & 7)) * 16);
    f32x4 acc[4][2] = {};
    gl_lds16(Ag0, (char*)As[0] + w * 2048);
    gl_lds16(Ag1, (char*)As[0] + w * 2048 + 1024);
    gl_lds16(Bg0, (char*)Bs[0] + w * 1024);
    __syncthreads();
    for (int kt = 0; kt < 32; kt++) {
        int bu = kt & 1;
        if (kt < 31) {
            gl_lds16(Ag0 + (kt + 1) * 64, (char*)As[bu ^ 1] + w * 2048);
            gl_lds16(Ag1 + (kt + 1) * 64, (char*)As[bu ^ 1] + w * 2048 + 1024);
            gl_lds16(Bg0 + (kt + 1) * 64, (char*)Bs[bu ^ 1] + w * 1024);
        }
        bf16x8 af[4], bfr[2];
        for (int mf = 0; mf < 4; mf++)
            af[mf] = *(bf16x8*)((char*)As[bu] + (mw + mf * 16) * 64 + cb);
        for (int nf = 0; nf < 2; nf++)
            bfr[nf] = *(bf16x8*)((char*)Bs[bu] + (nw + nf * 16) * 64 + cb);
        for (int mf = 0; mf < 4; mf++)
            for (int nf = 0; nf < 2; nf++)
                acc[mf][nf] = __builtin_amdgcn_mfma_f32_16x16x32_bf16(
                    af[mf], bfr[nf], acc[mf][nf], 0, 0, 0);
        __syncthreads();
    }
    for (int nf = 0; nf < 2; nf++) {
        int col = nt * 64 + nw + nf * 16 + c;
        float bv = bias[col];
        for (int mf = 0; mf < 4; mf++) {
            int m0 = mt * 128 + mw + mf * 16 + q * 4;
            float* dst = out + (size_t)m0 * 1024 + col;
            dst[0]    = acc[mf][nf][0] + bv;
            dst[1024] = acc[mf][nf][1] + bv;
            dst[2048] = acc[mf][nf][2] + bv;
            dst[3072] = acc[mf][nf][3] + bv;
        }
    }
}

extern "C" void kernel_launch(void* const* d_in, const int* in_sizes, int n_in,
                              void* d_out, int out_size, void* d_ws, size_t ws_size,
                              hipStream_t stream) {
    (void)in_sizes; (void)n_in; (void)out_size; (void)ws_size;
    const float* x     = (const float*)d_in[0];
    const float* w_qkv = (const float*)d_in[1];
    const float* w_out = (const float*)d_in[2];
    const float* b_out = (const float*)d_in[3];
    float* out = (float*)d_out;

    short* xb    = (short*)d_ws;
    short* wqkvt = xb    + 4096 * 1024;
    short* woutt = wqkvt + 3072 * 1024;
    short* Qb    = woutt + 1024 * 1024;
    short* Kb    = Qb    + BH * SEQ * HD;
    short* Vtb   = Kb    + BH * SEQ * HD;
    short* Ob    = Vtb   + BH * HD * SEQ;

    hipLaunchKernelGGL(prep, dim3(3072), dim3(256), 0, stream, x, w_qkv, w_out, xb, wqkvt, woutt);
    hipLaunchKernelGGL(gemm_qkv, dim3(768), dim3(256), 0, stream, xb, wqkvt, Qb, Kb, Vtb);
    hipLaunchKernelGGL(flash_attn, dim3(32, 16), dim3(512), 0, stream, Qb, Kb, Vtb, Ob);
    hipLaunchKernelGGL(gemm_out, dim3(512), dim3(256), 0, stream, Ob, woutt, b_out, out);
}

// Round 6
// 177.138 us; speedup vs baseline: 1.6628x; 1.1631x over previous
//
#include <hip/hip_runtime.h>
#include <stdint.h>

// Shapes (fixed by problem)
#define DIMD 1024
#define HEADS 16
#define HD 64
#define SEQ 2048
#define NBATCH 2
#define TOKENS 4096
#define BH 32

typedef __bf16 bf16x8 __attribute__((ext_vector_type(8)));
typedef float f32x4 __attribute__((ext_vector_type(4)));

#if __has_builtin(__builtin_amdgcn_exp2f)
#define EXP2(x) __builtin_amdgcn_exp2f(x)
#else
#define EXP2(x) exp2f(x)
#endif

#if __has_builtin(__builtin_amdgcn_cvt_pk_bf16_f32)
typedef __bf16 bf16x2 __attribute__((ext_vector_type(2)));
__device__ inline unsigned int pack2(float a, float b) {
    bf16x2 r = __builtin_amdgcn_cvt_pk_bf16_f32(a, b);
    return __builtin_bit_cast(unsigned int, r);
}
__device__ inline unsigned short f2bf(float f) {
    bf16x2 r = __builtin_amdgcn_cvt_pk_bf16_f32(f, f);
    return (unsigned short)(__builtin_bit_cast(unsigned int, r) & 0xffffu);
}
#else
__device__ inline unsigned short f2bf(float f) {
    unsigned int u = __builtin_bit_cast(unsigned int, f) + 0x8000u;
    return (unsigned short)(u >> 16);
}
__device__ inline unsigned int pack2(float a, float b) {
    unsigned int ua = __builtin_bit_cast(unsigned int, a) + 0x8000u;
    unsigned int ub = __builtin_bit_cast(unsigned int, b) + 0x8000u;
    return (ua >> 16) | (ub & 0xffff0000u);
}
#endif

// async global->LDS, 16B per lane, dest = wave-uniform base + lane*16
__device__ inline void gl_lds16(const void* g, void* l) {
    __builtin_amdgcn_global_load_lds(
        (const __attribute__((address_space(1))) unsigned int*)g,
        (__attribute__((address_space(3))) unsigned int*)l, 16, 0, 0);
}

// log2(e) * DIM^-0.5  (folded into Q at GEMM1 epilogue)
#define CEQ 0.0450842200277801f

// ------------- prep: cast x -> bf16 AND transpose-cast both weights ----
__global__ __launch_bounds__(256) void prep(const float* __restrict__ x,
                                            const float* __restrict__ wqkv,
                                            const float* __restrict__ wout,
                                            short* __restrict__ xb,
                                            short* __restrict__ wqkvt,
                                            short* __restrict__ woutt) {
    __shared__ short T[64 * 68];
    int bid = blockIdx.x, t = threadIdx.x;
    if (bid < 2048) {
        int g = bid * 256 + t;
        const float4* p = (const float4*)x + (size_t)g * 2;
        float4 a = p[0], b = p[1];
        uint4 o;
        o.x = pack2(a.x, a.y); o.y = pack2(a.z, a.w);
        o.z = pack2(b.x, b.y); o.w = pack2(b.z, b.w);
        ((uint4*)xb)[g] = o;
        return;
    }
    const float* w; short* wt; int N, n0, k0;
    if (bid < 2816) { int l = bid - 2048; w = wqkv; wt = wqkvt; N = 3072; n0 = (l % 48) * 64; k0 = (l / 48) * 64; }
    else            { int l = bid - 2816; w = wout; wt = woutt; N = 1024; n0 = (l % 16) * 64; k0 = (l / 16) * 64; }
    for (int e = 0; e < 4; e++) {
        int lin = t + e * 256;
        int r = lin >> 4, c = (lin & 15) * 4;
        float4 v = *(const float4*)(w + (size_t)(k0 + r) * N + n0 + c);
        *(uint2*)&T[r * 68 + c] = make_uint2(pack2(v.x, v.y), pack2(v.z, v.w));
    }
    __syncthreads();
    for (int e = 0; e < 4; e++) {
        int lin = t + e * 256;
        int nr = lin >> 4, kc = (lin & 15) * 4;
        unsigned short a0 = (unsigned short)T[(kc + 0) * 68 + nr];
        unsigned short a1 = (unsigned short)T[(kc + 1) * 68 + nr];
        unsigned short a2 = (unsigned short)T[(kc + 2) * 68 + nr];
        unsigned short a3 = (unsigned short)T[(kc + 3) * 68 + nr];
        *(uint2*)(wt + (size_t)(n0 + nr) * 1024 + k0 + kc) =
            make_uint2((unsigned int)a0 | ((unsigned int)a1 << 16),
                       (unsigned int)a2 | ((unsigned int)a3 << 16));
    }
}

// ---------------- GEMM1 (r10-proven) + T1 XCD-chunked swizzle ----------
// 768 blocks = 8 XCDs x 96: phys p (XCD p%8) -> work (p%8)*96 + p/8, so
// each XCD owns contiguous supertiles (shared A-panels stay in its L2).
__global__ __launch_bounds__(256) void gemm_qkv(const short* __restrict__ A,
                                                const short* __restrict__ Bt,
                                                short* __restrict__ Qb,
                                                short* __restrict__ Kb,
                                                short* __restrict__ Vtb) {
    __shared__ short As[2][128 * 32];
    __shared__ short Bs[2][128 * 32];
    int gid0 = blockIdx.x;
    int gid = (gid0 & 7) * 96 + (gid0 >> 3);   // bijective: 768 % 8 == 0
    int sg = gid >> 4, wi = gid & 15;
    int mt = (sg / 6) * 4 + (wi >> 2);
    int nt = (sg % 6) * 4 + (wi & 3);
    int t = threadIdx.x, w = t >> 6, lane = t & 63, c = lane & 15, q = lane >> 4;
    int mw = (w & 1) * 64, nw = (w >> 1) * 64;
    int h3 = lane >> 3, s3 = lane & 7, cp = s3 ^ h3;
    int rowin = 2 * h3 + (cp >> 2), koff = (cp & 3) * 16;
    const char* Ag0 = (const char*)A + (size_t)(mt * 128 + w * 32 + rowin) * 2048 + koff;
    const char* Ag1 = Ag0 + (size_t)16 * 2048;
    const char* Bg0 = (const char*)Bt + (size_t)(nt * 128 + w * 32 + rowin) * 2048 + koff;
    const char* Bg1 = Bg0 + (size_t)16 * 2048;
    int cb = (c >> 1) * 128 + ((((c & 1) * 4 + q) ^ ((c >> 1) & 7)) * 16);
    f32x4 acc[4][4] = {};
    gl_lds16(Ag0, (char*)As[0] + w * 2048);
    gl_lds16(Ag1, (char*)As[0] + w * 2048 + 1024);
    gl_lds16(Bg0, (char*)Bs[0] + w * 2048);
    gl_lds16(Bg1, (char*)Bs[0] + w * 2048 + 1024);
    __syncthreads();
    for (int kt = 0; kt < 32; kt++) {
        int bu = kt & 1;
        if (kt < 31) {
            gl_lds16(Ag0 + (kt + 1) * 64, (char*)As[bu ^ 1] + w * 2048);
            gl_lds16(Ag1 + (kt + 1) * 64, (char*)As[bu ^ 1] + w * 2048 + 1024);
            gl_lds16(Bg0 + (kt + 1) * 64, (char*)Bs[bu ^ 1] + w * 2048);
            gl_lds16(Bg1 + (kt + 1) * 64, (char*)Bs[bu ^ 1] + w * 2048 + 1024);
        }
        bf16x8 af[4], bfr[4];
        for (int mf = 0; mf < 4; mf++)
            af[mf] = *(bf16x8*)((char*)As[bu] + (mw + mf * 16) * 64 + cb);
        for (int nf = 0; nf < 4; nf++)
            bfr[nf] = *(bf16x8*)((char*)Bs[bu] + (nw + nf * 16) * 64 + cb);
        for (int mf = 0; mf < 4; mf++)
            for (int nf = 0; nf < 4; nf++)
                acc[mf][nf] = __builtin_amdgcn_mfma_f32_16x16x32_bf16(
                    af[mf], bfr[nf], acc[mf][nf], 0, 0, 0);
        __syncthreads();
    }
    for (int nf = 0; nf < 4; nf++) {
        int col = nt * 128 + nw + nf * 16 + c;
        int sel = col >> 10, cw = col & 1023, h = cw >> 6, d = cw & 63;
        float sc = (sel == 0) ? CEQ : 1.0f;
        for (int mf = 0; mf < 4; mf++) {
            int m0 = mt * 128 + mw + mf * 16 + q * 4;
            int b = m0 >> 11, nn = m0 & 2047;
            int bh = b * 16 + h;
            if (sel == 2) {
                *(uint2*)(Vtb + ((size_t)bh * 64 + d) * 2048 + nn) =
                    make_uint2(pack2(acc[mf][nf][0], acc[mf][nf][1]),
                               pack2(acc[mf][nf][2], acc[mf][nf][3]));
            } else {
                short* dst = (sel ? Kb : Qb) + ((size_t)bh * 2048 + nn) * 64 + d;
                dst[0]   = (short)f2bf(acc[mf][nf][0] * sc);
                dst[64]  = (short)f2bf(acc[mf][nf][1] * sc);
                dst[128] = (short)f2bf(acc[mf][nf][2] * sc);
                dst[192] = (short)f2bf(acc[mf][nf][3] * sc);
            }
        }
    }
}

// ---------------- flash attention v8 (r1-proven, 43 us): sigma-K staging,
// P stays in registers, K/V LDS double-buffered, 1 syncthreads per jt.
__global__ __launch_bounds__(512, 4) void flash_attn(const short* __restrict__ Qb,
                                                     const short* __restrict__ Kb,
                                                     const short* __restrict__ Vtb,
                                                     short* __restrict__ Ob) {
    __shared__ __align__(16) char smem[66048];
    char* ktp = smem;               // 2 x 16384 (K double-buffer)
    char* vtp = smem + 32768;       // 2 x 16384 (V double-buffer)
    float* lxp = (float*)(smem + 65536);
    int bh = blockIdx.x, qt = blockIdx.y;
    int t = threadIdx.x, w = t >> 6, lane = t & 63, c = lane & 15, q = lane >> 4;
    int wi = w & 3, hf = w >> 2;
    const short* Qh = Qb + (size_t)bh * SEQ * HD;
    bf16x8 bq[2][2];
    for (int i2 = 0; i2 < 2; i2++)
        for (int ks = 0; ks < 2; ks++)
            bq[i2][ks] = *(const bf16x8*)(Qh + (size_t)(qt * 128 + wi * 32 + i2 * 16 + c) * 64 + ks * 32 + q * 8);
    int rl = lane >> 3, sl = lane & 7, ch = sl ^ rl;
    // sigma-permuted K source row (within the 64-row jt tile), e adds +16:
    //   srow(e) = (wi>>1)*32 + e*16 + (rl>>2)*8 + (wi&1)*4 + (rl&3)
    int srow0 = (wi >> 1) * 32 + (rl >> 2) * 8 + (wi & 1) * 4 + (rl & 3);
    const char* Ksrc = (const char*)(Kb + (size_t)bh * SEQ * HD)
                       + (size_t)(hf * 1024 + srow0) * 128 + ch * 16;
    const char* Vsrc = (const char*)(Vtb + (size_t)bh * HD * SEQ)
                       + (size_t)(wi * 16 + rl) * 4096 + hf * 2048 + ch * 16;
    int sw0 = (q ^ (c & 7)) * 16;
    int sw1 = ((4 + q) ^ (c & 7)) * 16;
    bf16x8 ones;
    {
        unsigned short ob = 0x3F80;
        __bf16 ov = __builtin_bit_cast(__bf16, ob);
        for (int e = 0; e < 8; e++) ones[e] = ov;
    }
    f32x4 lacc[2] = {};
    f32x4 of[4][2] = {};
    // prologue: stage jt=0 into buffer 0
    {
        char* kb = ktp + hf * 8192 + wi * 2048;
        char* vb = vtp + hf * 8192 + wi * 2048;
        for (int e = 0; e < 2; e++) {
            gl_lds16(Ksrc + e * 2048, kb + e * 1024);
            gl_lds16(Vsrc + (size_t)e * 32768, vb + e * 1024);
        }
    }
    __syncthreads();
    for (int jt = 0; jt < 16; jt++) {
        int bu = jt & 1;
        if (jt < 15) {   // prefetch jt+1 into the other buffer, hidden under compute
            char* kb = ktp + (bu ^ 1) * 16384 + hf * 8192 + wi * 2048;
            char* vb = vtp + (bu ^ 1) * 16384 + hf * 8192 + wi * 2048;
            for (int e = 0; e < 2; e++) {
                gl_lds16(Ksrc + (size_t)(jt + 1) * 8192 + e * 2048, kb + e * 1024);
                gl_lds16(Vsrc + (size_t)(jt + 1) * 128 + (size_t)e * 32768, vb + e * 1024);
            }
        }
        const char* kth = ktp + bu * 16384 + hf * 8192;
        const char* vth = vtp + bu * 16384 + hf * 8192;
        f32x4 st[4][2] = {};
        for (int jf = 0; jf < 4; jf++) {
            bf16x8 ka0 = *(bf16x8*)(kth + (jf * 16 + c) * 128 + sw0);
            bf16x8 ka1 = *(bf16x8*)(kth + (jf * 16 + c) * 128 + sw1);
            for (int i2 = 0; i2 < 2; i2++)
                st[jf][i2] = __builtin_amdgcn_mfma_f32_16x16x32_bf16(
                    ka0, bq[i2][0], st[jf][i2], 0, 0, 0);
            for (int i2 = 0; i2 < 2; i2++)
                st[jf][i2] = __builtin_amdgcn_mfma_f32_16x16x32_bf16(
                    ka1, bq[i2][1], st[jf][i2], 0, 0, 0);
        }
        for (int ks = 0; ks < 2; ks++) {
            // exp2 + pack directly into the PV B-fragment (no LDS round-trip):
            // st[2ks][i2] regs 0..3 = k q*8+0..3, st[2ks+1][i2] regs 0..3 = k q*8+4..7
            bf16x8 pb[2];
            for (int i2 = 0; i2 < 2; i2++) {
                f32x4 sa = st[2 * ks][i2], sb = st[2 * ks + 1][i2];
                uint4 uu;
                uu.x = pack2(EXP2(sa[0]), EXP2(sa[1]));
                uu.y = pack2(EXP2(sa[2]), EXP2(sa[3]));
                uu.z = pack2(EXP2(sb[0]), EXP2(sb[1]));
                uu.w = pack2(EXP2(sb[2]), EXP2(sb[3]));
                pb[i2] = __builtin_bit_cast(bf16x8, uu);
            }
            int swk = ks ? sw1 : sw0;
            for (int mf = 0; mf < 4; mf++) {
                bf16x8 va = *(bf16x8*)(vth + (mf * 16 + c) * 128 + swk);
                for (int i2 = 0; i2 < 2; i2++)
                    of[mf][i2] = __builtin_amdgcn_mfma_f32_16x16x32_bf16(
                        va, pb[i2], of[mf][i2], 0, 0, 0);
            }
            for (int i2 = 0; i2 < 2; i2++)
                lacc[i2] = __builtin_amdgcn_mfma_f32_16x16x32_bf16(
                    ones, pb[i2], lacc[i2], 0, 0, 0);
        }
        __syncthreads();
    }
    float l0 = lacc[0][0], l1 = lacc[1][0];
    if (w >= 4) {
        float* ex = (float*)smem + (w - 4) * 2048;
        for (int mf = 0; mf < 4; mf++)
            for (int i2 = 0; i2 < 2; i2++)
                *(f32x4*)(ex + (mf * 2 + i2) * 256 + lane * 4) = of[mf][i2];
        if (lane < 16) { lxp[(w - 4) * 32 + lane] = l0; lxp[(w - 4) * 32 + 16 + lane] = l1; }
    }
    __syncthreads();
    if (w < 4) {
        float* ex = (float*)smem + w * 2048;
        for (int mf = 0; mf < 4; mf++)
            for (int i2 = 0; i2 < 2; i2++)
                of[mf][i2] += *(f32x4*)(ex + (mf * 2 + i2) * 256 + lane * 4);
        l0 += lxp[w * 32 + c];
        l1 += lxp[w * 32 + 16 + c];
        float inv0 = 1.f / l0, inv1 = 1.f / l1;
        short* plw = (short*)(smem + 32768 + w * 4608);   // reuse V region
        for (int mf = 0; mf < 4; mf++) {
            *(uint2*)(plw + (0 * 16 + c) * 72 + mf * 16 + q * 4) =
                make_uint2(pack2(of[mf][0][0] * inv0, of[mf][0][1] * inv0),
                           pack2(of[mf][0][2] * inv0, of[mf][0][3] * inv0));
            *(uint2*)(plw + (1 * 16 + c) * 72 + mf * 16 + q * 4) =
                make_uint2(pack2(of[mf][1][0] * inv1, of[mf][1][1] * inv1),
                           pack2(of[mf][1][2] * inv1, of[mf][1][3] * inv1));
        }
        int b2 = bh >> 4, h = bh & 15;
        for (int e = 0; e < 4; e++) {
            int chn = e * 64 + lane;
            int i = chn >> 3, db = (chn & 7) * 16;
            float4 v = *(float4*)((char*)plw + i * 144 + db);
            int token = b2 * 2048 + qt * 128 + w * 32 + i;
            *(float4*)((char*)Ob + (size_t)token * 2048 + h * 128 + db) = v;
        }
    }
}

// ---------------- GEMM2 (r12-proven) + T1 XCD-chunked swizzle ----------
__global__ __launch_bounds__(256) void gemm_out(const short* __restrict__ A,
                                                const short* __restrict__ Bt,
                                                const float* __restrict__ bias,
                                                float* __restrict__ out) {
    __shared__ short As[2][128 * 32];
    __shared__ short Bs[2][64 * 32];
    int gid0 = blockIdx.x;
    int gid = (gid0 & 7) * 64 + (gid0 >> 3);   // bijective: 512 % 8 == 0
    int sg = gid >> 4, wi = gid & 15;
    int mt = (sg / 4) * 4 + (wi >> 2);
    int nt = (sg % 4) * 4 + (wi & 3);
    int t = threadIdx.x, w = t >> 6, lane = t & 63, c = lane & 15, q = lane >> 4;
    int mw = (w & 1) * 64, nw = (w >> 1) * 32;
    int h3 = lane >> 3, s3 = lane & 7, cp = s3 ^ h3;
    int rowin = 2 * h3 + (cp >> 2), koff = (cp & 3) * 16;
    const char* Ag0 = (const char*)A + (size_t)(mt * 128 + w * 32 + rowin) * 2048 + koff;
    const char* Ag1 = Ag0 + (size_t)16 * 2048;
    const char* Bg0 = (const char*)Bt + (size_t)(nt * 64 + w * 16 + rowin) * 2048 + koff;
    int cb = (c >> 1) * 128 + ((((c & 1) * 4 + q) ^ ((c >> 1) & 7)) * 16);
    f32x4 acc[4][2] = {};
    gl_lds16(Ag0, (char*)As[0] + w * 2048);
    gl_lds16(Ag1, (char*)As[0] + w * 2048 + 1024);
    gl_lds16(Bg0, (char*)Bs[0] + w * 1024);
    __syncthreads();
    for (int kt = 0; kt < 32; kt++) {
        int bu = kt & 1;
        if (kt < 31) {
            gl_lds16(Ag0 + (kt + 1) * 64, (char*)As[bu ^ 1] + w * 2048);
            gl_lds16(Ag1 + (kt + 1) * 64, (char*)As[bu ^ 1] + w * 2048 + 1024);
            gl_lds16(Bg0 + (kt + 1) * 64, (char*)Bs[bu ^ 1] + w * 1024);
        }
        bf16x8 af[4], bfr[2];
        for (int mf = 0; mf < 4; mf++)
            af[mf] = *(bf16x8*)((char*)As[bu] + (mw + mf * 16) * 64 + cb);
        for (int nf = 0; nf < 2; nf++)
            bfr[nf] = *(bf16x8*)((char*)Bs[bu] + (nw + nf * 16) * 64 + cb);
        for (int mf = 0; mf < 4; mf++)
            for (int nf = 0; nf < 2; nf++)
                acc[mf][nf] = __builtin_amdgcn_mfma_f32_16x16x32_bf16(
                    af[mf], bfr[nf], acc[mf][nf], 0, 0, 0);
        __syncthreads();
    }
    for (int nf = 0; nf < 2; nf++) {
        int col = nt * 64 + nw + nf * 16 + c;
        float bv = bias[col];
        for (int mf = 0; mf < 4; mf++) {
            int m0 = mt * 128 + mw + mf * 16 + q * 4;
            float* dst = out + (size_t)m0 * 1024 + col;
            dst[0]    = acc[mf][nf][0] + bv;
            dst[1024] = acc[mf][nf][1] + bv;
            dst[2048] = acc[mf][nf][2] + bv;
            dst[3072] = acc[mf][nf][3] + bv;
        }
    }
}

extern "C" void kernel_launch(void* const* d_in, const int* in_sizes, int n_in,
                              void* d_out, int out_size, void* d_ws, size_t ws_size,
                              hipStream_t stream) {
    (void)in_sizes; (void)n_in; (void)out_size; (void)ws_size;
    const float* x     = (const float*)d_in[0];
    const float* w_qkv = (const float*)d_in[1];
    const float* w_out = (const float*)d_in[2];
    const float* b_out = (const float*)d_in[3];
    float* out = (float*)d_out;

    short* xb    = (short*)d_ws;
    short* wqkvt = xb    + 4096 * 1024;
    short* woutt = wqkvt + 3072 * 1024;
    short* Qb    = woutt + 1024 * 1024;
    short* Kb    = Qb    + BH * SEQ * HD;
    short* Vtb   = Kb    + BH * SEQ * HD;
    short* Ob    = Vtb   + BH * HD * SEQ;

    hipLaunchKernelGGL(prep, dim3(3072), dim3(256), 0, stream, x, w_qkv, w_out, xb, wqkvt, woutt);
    hipLaunchKernelGGL(gemm_qkv, dim3(768), dim3(256), 0, stream, xb, wqkvt, Qb, Kb, Vtb);
    hipLaunchKernelGGL(flash_attn, dim3(32, 16), dim3(512), 0, stream, Qb, Kb, Vtb, Ob);
    hipLaunchKernelGGL(gemm_out, dim3(512), dim3(256), 0, stream, Ob, woutt, b_out, out);
}

// Round 7
// 176.695 us; speedup vs baseline: 1.6670x; 1.0025x over previous
//
#include <hip/hip_runtime.h>
#include <stdint.h>

// Shapes (fixed by problem)
#define DIMD 1024
#define HEADS 16
#define HD 64
#define SEQ 2048
#define NBATCH 2
#define TOKENS 4096
#define BH 32

typedef __bf16 bf16x8 __attribute__((ext_vector_type(8)));
typedef float f32x4 __attribute__((ext_vector_type(4)));

#if __has_builtin(__builtin_amdgcn_exp2f)
#define EXP2(x) __builtin_amdgcn_exp2f(x)
#else
#define EXP2(x) exp2f(x)
#endif

#if __has_builtin(__builtin_amdgcn_cvt_pk_bf16_f32)
typedef __bf16 bf16x2 __attribute__((ext_vector_type(2)));
__device__ inline unsigned int pack2(float a, float b) {
    bf16x2 r = __builtin_amdgcn_cvt_pk_bf16_f32(a, b);
    return __builtin_bit_cast(unsigned int, r);
}
__device__ inline unsigned short f2bf(float f) {
    bf16x2 r = __builtin_amdgcn_cvt_pk_bf16_f32(f, f);
    return (unsigned short)(__builtin_bit_cast(unsigned int, r) & 0xffffu);
}
#else
__device__ inline unsigned short f2bf(float f) {
    unsigned int u = __builtin_bit_cast(unsigned int, f) + 0x8000u;
    return (unsigned short)(u >> 16);
}
__device__ inline unsigned int pack2(float a, float b) {
    unsigned int ua = __builtin_bit_cast(unsigned int, a) + 0x8000u;
    unsigned int ub = __builtin_bit_cast(unsigned int, b) + 0x8000u;
    return (ua >> 16) | (ub & 0xffff0000u);
}
#endif

// async global->LDS, 16B per lane, dest = wave-uniform base + lane*16
__device__ inline void gl_lds16(const void* g, void* l) {
    __builtin_amdgcn_global_load_lds(
        (const __attribute__((address_space(1))) unsigned int*)g,
        (__attribute__((address_space(3))) unsigned int*)l, 16, 0, 0);
}

// log2(e) * DIM^-0.5  (folded into Q at GEMM1 epilogue)
#define CEQ 0.0450842200277801f

// ------------- prep: cast x -> bf16 AND transpose-cast both weights ----
__global__ __launch_bounds__(256) void prep(const float* __restrict__ x,
                                            const float* __restrict__ wqkv,
                                            const float* __restrict__ wout,
                                            short* __restrict__ xb,
                                            short* __restrict__ wqkvt,
                                            short* __restrict__ woutt) {
    __shared__ short T[64 * 68];
    int bid = blockIdx.x, t = threadIdx.x;
    if (bid < 2048) {
        int g = bid * 256 + t;
        const float4* p = (const float4*)x + (size_t)g * 2;
        float4 a = p[0], b = p[1];
        uint4 o;
        o.x = pack2(a.x, a.y); o.y = pack2(a.z, a.w);
        o.z = pack2(b.x, b.y); o.w = pack2(b.z, b.w);
        ((uint4*)xb)[g] = o;
        return;
    }
    const float* w; short* wt; int N, n0, k0;
    if (bid < 2816) { int l = bid - 2048; w = wqkv; wt = wqkvt; N = 3072; n0 = (l % 48) * 64; k0 = (l / 48) * 64; }
    else            { int l = bid - 2816; w = wout; wt = woutt; N = 1024; n0 = (l % 16) * 64; k0 = (l / 16) * 64; }
    for (int e = 0; e < 4; e++) {
        int lin = t + e * 256;
        int r = lin >> 4, c = (lin & 15) * 4;
        float4 v = *(const float4*)(w + (size_t)(k0 + r) * N + n0 + c);
        *(uint2*)&T[r * 68 + c] = make_uint2(pack2(v.x, v.y), pack2(v.z, v.w));
    }
    __syncthreads();
    for (int e = 0; e < 4; e++) {
        int lin = t + e * 256;
        int nr = lin >> 4, kc = (lin & 15) * 4;
        unsigned short a0 = (unsigned short)T[(kc + 0) * 68 + nr];
        unsigned short a1 = (unsigned short)T[(kc + 1) * 68 + nr];
        unsigned short a2 = (unsigned short)T[(kc + 2) * 68 + nr];
        unsigned short a3 = (unsigned short)T[(kc + 3) * 68 + nr];
        *(uint2*)(wt + (size_t)(n0 + nr) * 1024 + k0 + kc) =
            make_uint2((unsigned int)a0 | ((unsigned int)a1 << 16),
                       (unsigned int)a2 | ((unsigned int)a3 << 16));
    }
}

// ---------------- GEMM1 (r10-proven) + T1 XCD-chunked swizzle ----------
__global__ __launch_bounds__(256) void gemm_qkv(const short* __restrict__ A,
                                                const short* __restrict__ Bt,
                                                short* __restrict__ Qb,
                                                short* __restrict__ Kb,
                                                short* __restrict__ Vtb) {
    __shared__ short As[2][128 * 32];
    __shared__ short Bs[2][128 * 32];
    int gid0 = blockIdx.x;
    int gid = (gid0 & 7) * 96 + (gid0 >> 3);   // bijective: 768 % 8 == 0
    int sg = gid >> 4, wi = gid & 15;
    int mt = (sg / 6) * 4 + (wi >> 2);
    int nt = (sg % 6) * 4 + (wi & 3);
    int t = threadIdx.x, w = t >> 6, lane = t & 63, c = lane & 15, q = lane >> 4;
    int mw = (w & 1) * 64, nw = (w >> 1) * 64;
    int h3 = lane >> 3, s3 = lane & 7, cp = s3 ^ h3;
    int rowin = 2 * h3 + (cp >> 2), koff = (cp & 3) * 16;
    const char* Ag0 = (const char*)A + (size_t)(mt * 128 + w * 32 + rowin) * 2048 + koff;
    const char* Ag1 = Ag0 + (size_t)16 * 2048;
    const char* Bg0 = (const char*)Bt + (size_t)(nt * 128 + w * 32 + rowin) * 2048 + koff;
    const char* Bg1 = Bg0 + (size_t)16 * 2048;
    int cb = (c >> 1) * 128 + ((((c & 1) * 4 + q) ^ ((c >> 1) & 7)) * 16);
    f32x4 acc[4][4] = {};
    gl_lds16(Ag0, (char*)As[0] + w * 2048);
    gl_lds16(Ag1, (char*)As[0] + w * 2048 + 1024);
    gl_lds16(Bg0, (char*)Bs[0] + w * 2048);
    gl_lds16(Bg1, (char*)Bs[0] + w * 2048 + 1024);
    __syncthreads();
    for (int kt = 0; kt < 32; kt++) {
        int bu = kt & 1;
        if (kt < 31) {
            gl_lds16(Ag0 + (kt + 1) * 64, (char*)As[bu ^ 1] + w * 2048);
            gl_lds16(Ag1 + (kt + 1) * 64, (char*)As[bu ^ 1] + w * 2048 + 1024);
            gl_lds16(Bg0 + (kt + 1) * 64, (char*)Bs[bu ^ 1] + w * 2048);
            gl_lds16(Bg1 + (kt + 1) * 64, (char*)Bs[bu ^ 1] + w * 2048 + 1024);
        }
        bf16x8 af[4], bfr[4];
        for (int mf = 0; mf < 4; mf++)
            af[mf] = *(bf16x8*)((char*)As[bu] + (mw + mf * 16) * 64 + cb);
        for (int nf = 0; nf < 4; nf++)
            bfr[nf] = *(bf16x8*)((char*)Bs[bu] + (nw + nf * 16) * 64 + cb);
        for (int mf = 0; mf < 4; mf++)
            for (int nf = 0; nf < 4; nf++)
                acc[mf][nf] = __builtin_amdgcn_mfma_f32_16x16x32_bf16(
                    af[mf], bfr[nf], acc[mf][nf], 0, 0, 0);
        __syncthreads();
    }
    for (int nf = 0; nf < 4; nf++) {
        int col = nt * 128 + nw + nf * 16 + c;
        int sel = col >> 10, cw = col & 1023, h = cw >> 6, d = cw & 63;
        float sc = (sel == 0) ? CEQ : 1.0f;
        for (int mf = 0; mf < 4; mf++) {
            int m0 = mt * 128 + mw + mf * 16 + q * 4;
            int b = m0 >> 11, nn = m0 & 2047;
            int bh = b * 16 + h;
            if (sel == 2) {
                *(uint2*)(Vtb + ((size_t)bh * 64 + d) * 2048 + nn) =
                    make_uint2(pack2(acc[mf][nf][0], acc[mf][nf][1]),
                               pack2(acc[mf][nf][2], acc[mf][nf][3]));
            } else {
                short* dst = (sel ? Kb : Qb) + ((size_t)bh * 2048 + nn) * 64 + d;
                dst[0]   = (short)f2bf(acc[mf][nf][0] * sc);
                dst[64]  = (short)f2bf(acc[mf][nf][1] * sc);
                dst[128] = (short)f2bf(acc[mf][nf][2] * sc);
                dst[192] = (short)f2bf(acc[mf][nf][3] * sc);
            }
        }
    }
}

// ---------------- flash attention v14: v8 math, 3 blocks/CU.
// V single-buffered (LDS 51712 -> 3 blocks/CU = 24 waves). Software
// pipeline per jt: barrierA (drains V(jt),K(jt+1) staged last iter) ->
// PV(jt) -> barrierB (Vb reads retired) -> stage V(jt+1),K(jt+2) ->
// QK(jt+1)+exp (pb2 carried in regs). Every stage has a full QK+exp
// phase before its draining barrier; no inline-asm waitcnt anywhere.
__global__ __launch_bounds__(512, 4) void flash_attn(const short* __restrict__ Qb,
                                                     const short* __restrict__ Kb,
                                                     const short* __restrict__ Vtb,
                                                     short* __restrict__ Ob) {
    __shared__ __align__(16) char smem[51712];
    char* Kb0 = smem;               // 16 KB K buffer 0
    char* Kb1 = smem + 16384;       // 16 KB K buffer 1
    char* Vb  = smem + 32768;       // 16 KB V single buffer
    float* lxp = (float*)(smem + 51200);
    int bh = blockIdx.x, qt = blockIdx.y;
    int t = threadIdx.x, w = t >> 6, lane = t & 63, c = lane & 15, q = lane >> 4;
    int wi = w & 3, hf = w >> 2;
    const short* Qh = Qb + (size_t)bh * SEQ * HD;
    bf16x8 bq[2][2];
    for (int i2 = 0; i2 < 2; i2++)
        for (int ks = 0; ks < 2; ks++)
            bq[i2][ks] = *(const bf16x8*)(Qh + (size_t)(qt * 128 + wi * 32 + i2 * 16 + c) * 64 + ks * 32 + q * 8);
    int rl = lane >> 3, sl = lane & 7, ch = sl ^ rl;
    // sigma-permuted K source row (within the 64-row jt tile), e adds +16:
    //   srow(e) = (wi>>1)*32 + e*16 + (rl>>2)*8 + (wi&1)*4 + (rl&3)
    int srow0 = (wi >> 1) * 32 + (rl >> 2) * 8 + (wi & 1) * 4 + (rl & 3);
    const char* Ksrc = (const char*)(Kb + (size_t)bh * SEQ * HD)
                       + (size_t)(hf * 1024 + srow0) * 128 + ch * 16;
    const char* Vsrc = (const char*)(Vtb + (size_t)bh * HD * SEQ)
                       + (size_t)(wi * 16 + rl) * 4096 + hf * 2048 + ch * 16;
    int sw0 = (q ^ (c & 7)) * 16;
    int sw1 = ((4 + q) ^ (c & 7)) * 16;
    bf16x8 ones;
    {
        unsigned short ob = 0x3F80;
        __bf16 ov = __builtin_bit_cast(__bf16, ob);
        for (int e = 0; e < 8; e++) ones[e] = ov;
    }
    f32x4 lacc[2] = {};
    f32x4 of[4][2] = {};
    bf16x8 pb2[2][2];
    int kdo = hf * 8192 + wi * 2048;
    // prologue: K(0)->Kb0, V(0)->Vb, K(1)->Kb1
    gl_lds16(Ksrc, Kb0 + kdo);
    gl_lds16(Ksrc + 2048, Kb0 + kdo + 1024);
    gl_lds16(Vsrc, Vb + kdo);
    gl_lds16(Vsrc + 32768, Vb + kdo + 1024);
    gl_lds16(Ksrc + 8192, Kb1 + kdo);
    gl_lds16(Ksrc + 8192 + 2048, Kb1 + kdo + 1024);
    __syncthreads();
    // QK(0) + exp -> pb2
    {
        const char* kth = Kb0 + hf * 8192;
        f32x4 st[4][2] = {};
#pragma unroll
        for (int jf = 0; jf < 4; jf++) {
            bf16x8 ka0 = *(bf16x8*)(kth + (jf * 16 + c) * 128 + sw0);
            bf16x8 ka1 = *(bf16x8*)(kth + (jf * 16 + c) * 128 + sw1);
            for (int i2 = 0; i2 < 2; i2++)
                st[jf][i2] = __builtin_amdgcn_mfma_f32_16x16x32_bf16(ka0, bq[i2][0], st[jf][i2], 0, 0, 0);
            for (int i2 = 0; i2 < 2; i2++)
                st[jf][i2] = __builtin_amdgcn_mfma_f32_16x16x32_bf16(ka1, bq[i2][1], st[jf][i2], 0, 0, 0);
        }
#pragma unroll
        for (int ks = 0; ks < 2; ks++)
#pragma unroll
            for (int i2 = 0; i2 < 2; i2++) {
                f32x4 sa = st[2 * ks][i2], sb = st[2 * ks + 1][i2];
                uint4 uu;
                uu.x = pack2(EXP2(sa[0]), EXP2(sa[1]));
                uu.y = pack2(EXP2(sa[2]), EXP2(sa[3]));
                uu.z = pack2(EXP2(sb[0]), EXP2(sb[1]));
                uu.w = pack2(EXP2(sb[2]), EXP2(sb[3]));
                pb2[ks][i2] = __builtin_bit_cast(bf16x8, uu);
            }
    }
    for (int jt = 0; jt < 16; jt++) {
        __syncthreads();   // A: V(jt) and K(jt+1) staged last iter now drained
        const char* vth = Vb + hf * 8192;
#pragma unroll
        for (int ks = 0; ks < 2; ks++) {
            int swk = ks ? sw1 : sw0;
#pragma unroll
            for (int mf = 0; mf < 4; mf++) {
                bf16x8 va = *(bf16x8*)(vth + (mf * 16 + c) * 128 + swk);
                for (int i2 = 0; i2 < 2; i2++)
                    of[mf][i2] = __builtin_amdgcn_mfma_f32_16x16x32_bf16(
                        va, pb2[ks][i2], of[mf][i2], 0, 0, 0);
            }
            for (int i2 = 0; i2 < 2; i2++)
                lacc[i2] = __builtin_amdgcn_mfma_f32_16x16x32_bf16(
                    ones, pb2[ks][i2], lacc[i2], 0, 0, 0);
        }
        __syncthreads();   // B: all Vb reads retired
        if (jt < 15) {
            // stage V(jt+1) into Vb; K(jt+2) into the K buffer read at QK(jt)
            gl_lds16(Vsrc + (size_t)(jt + 1) * 128, Vb + kdo);
            gl_lds16(Vsrc + (size_t)(jt + 1) * 128 + 32768, Vb + kdo + 1024);
            if (jt < 14) {
                char* kdst = (jt & 1 ? Kb1 : Kb0) + kdo;
                gl_lds16(Ksrc + (size_t)(jt + 2) * 8192, kdst);
                gl_lds16(Ksrc + (size_t)(jt + 2) * 8192 + 2048, kdst + 1024);
            }
            // QK(jt+1) from the other K buffer (staged >=1 drain ago)
            const char* kth = ((jt + 1) & 1 ? Kb1 : Kb0) + hf * 8192;
            f32x4 st[4][2] = {};
#pragma unroll
            for (int jf = 0; jf < 4; jf++) {
                bf16x8 ka0 = *(bf16x8*)(kth + (jf * 16 + c) * 128 + sw0);
                bf16x8 ka1 = *(bf16x8*)(kth + (jf * 16 + c) * 128 + sw1);
                for (int i2 = 0; i2 < 2; i2++)
                    st[jf][i2] = __builtin_amdgcn_mfma_f32_16x16x32_bf16(ka0, bq[i2][0], st[jf][i2], 0, 0, 0);
                for (int i2 = 0; i2 < 2; i2++)
                    st[jf][i2] = __builtin_amdgcn_mfma_f32_16x16x32_bf16(ka1, bq[i2][1], st[jf][i2], 0, 0, 0);
            }
#pragma unroll
            for (int ks = 0; ks < 2; ks++)
#pragma unroll
                for (int i2 = 0; i2 < 2; i2++) {
                    f32x4 sa = st[2 * ks][i2], sb = st[2 * ks + 1][i2];
                    uint4 uu;
                    uu.x = pack2(EXP2(sa[0]), EXP2(sa[1]));
                    uu.y = pack2(EXP2(sa[2]), EXP2(sa[3]));
                    uu.z = pack2(EXP2(sb[0]), EXP2(sb[1]));
                    uu.w = pack2(EXP2(sb[2]), EXP2(sb[3]));
                    pb2[ks][i2] = __builtin_bit_cast(bf16x8, uu);
                }
        }
    }
    float l0 = lacc[0][0], l1 = lacc[1][0];
    if (w >= 4) {
        float* ex = (float*)smem + (w - 4) * 2048;
        for (int mf = 0; mf < 4; mf++)
            for (int i2 = 0; i2 < 2; i2++)
                *(f32x4*)(ex + (mf * 2 + i2) * 256 + lane * 4) = of[mf][i2];
        if (lane < 16) { lxp[(w - 4) * 32 + lane] = l0; lxp[(w - 4) * 32 + 16 + lane] = l1; }
    }
    __syncthreads();
    if (w < 4) {
        float* ex = (float*)smem + w * 2048;
        for (int mf = 0; mf < 4; mf++)
            for (int i2 = 0; i2 < 2; i2++)
                of[mf][i2] += *(f32x4*)(ex + (mf * 2 + i2) * 256 + lane * 4);
        l0 += lxp[w * 32 + c];
        l1 += lxp[w * 32 + 16 + c];
        float inv0 = 1.f / l0, inv1 = 1.f / l1;
        short* plw = (short*)(smem + 32768 + w * 4608);   // V region, ends at 51200
        for (int mf = 0; mf < 4; mf++) {
            *(uint2*)(plw + (0 * 16 + c) * 72 + mf * 16 + q * 4) =
                make_uint2(pack2(of[mf][0][0] * inv0, of[mf][0][1] * inv0),
                           pack2(of[mf][0][2] * inv0, of[mf][0][3] * inv0));
            *(uint2*)(plw + (1 * 16 + c) * 72 + mf * 16 + q * 4) =
                make_uint2(pack2(of[mf][1][0] * inv1, of[mf][1][1] * inv1),
                           pack2(of[mf][1][2] * inv1, of[mf][1][3] * inv1));
        }
        int b2 = bh >> 4, h = bh & 15;
        for (int e = 0; e < 4; e++) {
            int chn = e * 64 + lane;
            int i = chn >> 3, db = (chn & 7) * 16;
            float4 v = *(float4*)((char*)plw + i * 144 + db);
            int token = b2 * 2048 + qt * 128 + w * 32 + i;
            *(float4*)((char*)Ob + (size_t)token * 2048 + h * 128 + db) = v;
        }
    }
}

// ---------------- GEMM2 (r12-proven) + T1 XCD-chunked swizzle ----------
__global__ __launch_bounds__(256) void gemm_out(const short* __restrict__ A,
                                                const short* __restrict__ Bt,
                                                const float* __restrict__ bias,
                                                float* __restrict__ out) {
    __shared__ short As[2][128 * 32];
    __shared__ short Bs[2][64 * 32];
    int gid0 = blockIdx.x;
    int gid = (gid0 & 7) * 64 + (gid0 >> 3);   // bijective: 512 % 8 == 0
    int sg = gid >> 4, wi = gid & 15;
    int mt = (sg / 4) * 4 + (wi >> 2);
    int nt = (sg % 4) * 4 + (wi & 3);
    int t = threadIdx.x, w = t >> 6, lane = t & 63, c = lane & 15, q = lane >> 4;
    int mw = (w & 1) * 64, nw = (w >> 1) * 32;
    int h3 = lane >> 3, s3 = lane & 7, cp = s3 ^ h3;
    int rowin = 2 * h3 + (cp >> 2), koff = (cp & 3) * 16;
    const char* Ag0 = (const char*)A + (size_t)(mt * 128 + w * 32 + rowin) * 2048 + koff;
    const char* Ag1 = Ag0 + (size_t)16 * 2048;
    const char* Bg0 = (const char*)Bt + (size_t)(nt * 64 + w * 16 + rowin) * 2048 + koff;
    int cb = (c >> 1) * 128 + ((((c & 1) * 4 + q) ^ ((c >> 1) & 7)) * 16);
    f32x4 acc[4][2] = {};
    gl_lds16(Ag0, (char*)As[0] + w * 2048);
    gl_lds16(Ag1, (char*)As[0] + w * 2048 + 1024);
    gl_lds16(Bg0, (char*)Bs[0] + w * 1024);
    __syncthreads();
    for (int kt = 0; kt < 32; kt++) {
        int bu = kt & 1;
        if (kt < 31) {
            gl_lds16(Ag0 + (kt + 1) * 64, (char*)As[bu ^ 1] + w * 2048);
            gl_lds16(Ag1 + (kt + 1) * 64, (char*)As[bu ^ 1] + w * 2048 + 1024);
            gl_lds16(Bg0 + (kt + 1) * 64, (char*)Bs[bu ^ 1] + w * 1024);
        }
        bf16x8 af[4], bfr[2];
        for (int mf = 0; mf < 4; mf++)
            af[mf] = *(bf16x8*)((char*)As[bu] + (mw + mf * 16) * 64 + cb);
        for (int nf = 0; nf < 2; nf++)
            bfr[nf] = *(bf16x8*)((char*)Bs[bu] + (nw + nf * 16) * 64 + cb);
        for (int mf = 0; mf < 4; mf++)
            for (int nf = 0; nf < 2; nf++)
                acc[mf][nf] = __builtin_amdgcn_mfma_f32_16x16x32_bf16(
                    af[mf], bfr[nf], acc[mf][nf], 0, 0, 0);
        __syncthreads();
    }
    for (int nf = 0; nf < 2; nf++) {
        int col = nt * 64 + nw + nf * 16 + c;
        float bv = bias[col];
        for (int mf = 0; mf < 4; mf++) {
            int m0 = mt * 128 + mw + mf * 16 + q * 4;
            float* dst = out + (size_t)m0 * 1024 + col;
            dst[0]    = acc[mf][nf][0] + bv;
            dst[1024] = acc[mf][nf][1] + bv;
            dst[2048] = acc[mf][nf][2] + bv;
            dst[3072] = acc[mf][nf][3] + bv;
        }
    }
}

extern "C" void kernel_launch(void* const* d_in, const int* in_sizes, int n_in,
                              void* d_out, int out_size, void* d_ws, size_t ws_size,
                              hipStream_t stream) {
    (void)in_sizes; (void)n_in; (void)out_size; (void)ws_size;
    const float* x     = (const float*)d_in[0];
    const float* w_qkv = (const float*)d_in[1];
    const float* w_out = (const float*)d_in[2];
    const float* b_out = (const float*)d_in[3];
    float* out = (float*)d_out;

    short* xb    = (short*)d_ws;
    short* wqkvt = xb    + 4096 * 1024;
    short* woutt = wqkvt + 3072 * 1024;
    short* Qb    = woutt + 1024 * 1024;
    short* Kb    = Qb    + BH * SEQ * HD;
    short* Vtb   = Kb    + BH * SEQ * HD;
    short* Ob    = Vtb   + BH * HD * SEQ;

    hipLaunchKernelGGL(prep, dim3(3072), dim3(256), 0, stream, x, w_qkv, w_out, xb, wqkvt, woutt);
    hipLaunchKernelGGL(gemm_qkv, dim3(768), dim3(256), 0, stream, xb, wqkvt, Qb, Kb, Vtb);
    hipLaunchKernelGGL(flash_attn, dim3(32, 16), dim3(512), 0, stream, Qb, Kb, Vtb, Ob);
    hipLaunchKernelGGL(gemm_out, dim3(512), dim3(256), 0, stream, Ob, woutt, b_out, out);
}